// Round 4
// baseline (101.117 us; speedup 1.0000x reference)
//
#include <hip/hip_runtime.h>
#include <math.h>

#define BS 16
#define NPTS 2048
#define MPTS 2048
#define KSEG 32
#define DDIM 128

// ws float layout (NO zero-init required: every word read is written earlier
// in the same call — harness re-poisons ws to 0xAA before every launch)
#define OFF_XN    0                       // [0, 32768)            bs*N
#define OFF_PART  32768                   // [32768, 294912)       8 sg * bs*N
#define OFF_SEGP  294912                  // [294912, 319488)      3 * bs * 16 * 32
#define OFF_LOSSP 319488                  // [319488, 319552)      2 * 32
#define OFF_CNT   319552                  // ticket counter (uint), zeroed by seg

// grid 512: b(16) x tile(4, 512 points each) x sg(8, 256 m each).
// Block = 4 waves; wave w scans m-slice [sg*256 + w*64, +64); each lane holds
// 8 points (p = tile*512 + 64j + lane). score = 0.5|y|^2 - x.y ;
// d2 = xn + 2*min(score), finalized in seg_kernel.
__global__ __launch_bounds__(256) void cham_kernel(
    const float* __restrict__ pc_partial, const float* __restrict__ deformed,
    const float* __restrict__ p_rot, const float* __restrict__ p_t,
    const float* __restrict__ f_rot, const float* __restrict__ f_t,
    const float* __restrict__ tg_rot, const float* __restrict__ tg_t,
    const float* __restrict__ sr_rot, const float* __restrict__ sr_t,
    float* __restrict__ xnArr, float* __restrict__ part)
{
    __shared__ float4 sh_y[256];     // 4 KB
    __shared__ float pmin[4][512];   // 8 KB

    const int bid  = blockIdx.x;
    const int b    = bid >> 5;
    const int r    = bid & 31;
    const int tile = r & 3;
    const int sg   = r >> 2;
    const int t = threadIdx.x;
    const int l = t & 63;
    const int w = t >> 6;

    // stage this block's 256-m slice as {y, 0.5*|y|^2} (overlaps xform math)
    const float* def0 = deformed + (size_t)b * 3 * MPTS + sg * 256;
    {
        float y0 = def0[t], y1 = def0[MPTS + t], y2 = def0[2*MPTS + t];
        sh_y[t] = make_float4(y0, y1, y2, 0.5f*(y0*y0 + y1*y1 + y2*y2));
    }

    // fold the 5-transform chain into one affine (row-vector convention):
    // x = p @ R + T, R = ((P @ Tg^T) @ Sr) @ F^T,
    // T = (((p_t - tg_t) @ Tg^T) @ Sr + sr_t - f_t) @ F^T
    float R[9], T[3];
    {
        float P[9], F[9], Tg[9], Sr[9];
#pragma unroll
        for (int i = 0; i < 9; i++) {
            P[i] = p_rot[b*9+i];  F[i] = f_rot[b*9+i];
            Tg[i] = tg_rot[b*9+i]; Sr[i] = sr_rot[b*9+i];
        }
        float A[9], Bm[9];
#pragma unroll
        for (int i = 0; i < 3; i++)
#pragma unroll
            for (int j = 0; j < 3; j++)
                A[i*3+j] = P[i*3+0]*Tg[j*3+0] + P[i*3+1]*Tg[j*3+1] + P[i*3+2]*Tg[j*3+2];
#pragma unroll
        for (int i = 0; i < 3; i++)
#pragma unroll
            for (int j = 0; j < 3; j++)
                Bm[i*3+j] = A[i*3+0]*Sr[0*3+j] + A[i*3+1]*Sr[1*3+j] + A[i*3+2]*Sr[2*3+j];
#pragma unroll
        for (int i = 0; i < 3; i++)
#pragma unroll
            for (int j = 0; j < 3; j++)
                R[i*3+j] = Bm[i*3+0]*F[j*3+0] + Bm[i*3+1]*F[j*3+1] + Bm[i*3+2]*F[j*3+2];
        float t0[3], t1[3], t2[3], t3[3];
#pragma unroll
        for (int i = 0; i < 3; i++) t0[i] = p_t[b*3+i] - tg_t[b*3+i];
#pragma unroll
        for (int j = 0; j < 3; j++)
            t1[j] = t0[0]*Tg[j*3+0] + t0[1]*Tg[j*3+1] + t0[2]*Tg[j*3+2];
#pragma unroll
        for (int j = 0; j < 3; j++)
            t2[j] = t1[0]*Sr[0*3+j] + t1[1]*Sr[1*3+j] + t1[2]*Sr[2*3+j];
#pragma unroll
        for (int i = 0; i < 3; i++) t3[i] = t2[i] + sr_t[b*3+i] - f_t[b*3+i];
#pragma unroll
        for (int j = 0; j < 3; j++)
            T[j] = t3[0]*F[j*3+0] + t3[1]*F[j*3+1] + t3[2]*F[j*3+2];
    }

    float x0[8], x1[8], x2[8], mn[8];
    const int nbase = tile * 512 + l;
    const float* pcb = pc_partial + (size_t)b * NPTS * 3;
#pragma unroll
    for (int j = 0; j < 8; j++) {
        const float* pc = pcb + (size_t)(nbase + 64*j) * 3;
        float px = pc[0], py = pc[1], pz = pc[2];
        x0[j] = px*R[0] + py*R[3] + pz*R[6] + T[0];
        x1[j] = px*R[1] + py*R[4] + pz*R[7] + T[1];
        x2[j] = px*R[2] + py*R[5] + pz*R[8] + T[2];
        mn[j] = 3.402823466e+38f;
    }
    if (sg == 0 && w == 0) {
#pragma unroll
        for (int j = 0; j < 8; j++)
            xnArr[(size_t)b*NPTS + nbase + 64*j] =
                x0[j]*x0[j] + x1[j]*x1[j] + x2[j]*x2[j];
    }
    __syncthreads();

    const int mb = w * 64;
#pragma unroll 4
    for (int i = 0; i < 64; i++) {
        float4 y = sh_y[mb + i];                 // wave-uniform broadcast
#pragma unroll
        for (int j = 0; j < 8; j++) {
            float s = fmaf(-x2[j], y.z, fmaf(-x1[j], y.y, fmaf(-x0[j], y.x, y.w)));
            mn[j] = fminf(mn[j], s);
        }
    }

#pragma unroll
    for (int j = 0; j < 8; j++) pmin[w][64*j + l] = mn[j];
    __syncthreads();

    // reduce across 4 wave-slices; write coalesced [sg][b][n]
#pragma unroll
    for (int u = 0; u < 2; u++) {
        int p = t + 256 * u;
        float v = fminf(fminf(pmin[0][p], pmin[1][p]),
                        fminf(pmin[2][p], pmin[3][p]));
        part[(size_t)sg * (BS*NPTS) + (size_t)b * NPTS + tile*512 + p] = v;
    }
}

// grid: BS * 16 = 256 blocks; block (b,nc) finalizes cham for 128 n rows +
// per-block segment partial sums. Thread t reads flat float4 slots t+256u:
// every wave-instr is 1 KB contiguous; each thread keeps one k4 column.
__global__ __launch_bounds__(256) void seg_kernel(
    const float* __restrict__ seg_p, const float* __restrict__ seg_f,
    const float* __restrict__ xnArr, const float* __restrict__ part,
    float* __restrict__ ws)
{
    __shared__ float chamLDS[128];
    __shared__ float red0[1024], red1[1024], red2[1024];  // 12 KB

    const int b = blockIdx.x >> 4;
    const int nc = blockIdx.x & 15;
    const int t = threadIdx.x;
    const int n0 = nc * 128;

    if (t == 0) ((unsigned int*)ws)[OFF_CNT] = 0u;   // ticket for loss_kernel

    if (t < 128) {
        const size_t nidx = (size_t)b * NPTS + n0 + t;
        float xn = xnArr[nidx];
        float pm = part[nidx];
#pragma unroll
        for (int sg = 1; sg < 8; sg++)
            pm = fminf(pm, part[(size_t)sg * (BS*NPTS) + nidx]);
        chamLDS[t] = fmaxf(fmaf(2.0f, pm, xn), 0.0f);
    }
    __syncthreads();

    const int g  = t >> 3;   // row group 0..31
    const int k4 = t & 7;    // float4 column (segments 4*k4..4*k4+3)
    const float4* sp4 = (const float4*)(seg_p + ((size_t)b * NPTS + n0) * KSEG);
    const float4* sf4 = (const float4*)(seg_f + ((size_t)b * NPTS + n0) * KSEG);

    float4 ap = make_float4(0.f,0.f,0.f,0.f);
    float4 af = make_float4(0.f,0.f,0.f,0.f);
    float4 a2 = make_float4(0.f,0.f,0.f,0.f);
#pragma unroll
    for (int u = 0; u < 4; u++) {
        int row = g + 32 * u;
        float c = chamLDS[row];                  // 8-lane broadcast
        float4 vp = sp4[row * 8 + k4];           // flat slot t + 256u
        float4 vf = sf4[row * 8 + k4];
        ap.x += vp.x; ap.y += vp.y; ap.z += vp.z; ap.w += vp.w;
        af.x += vf.x; af.y += vf.y; af.z += vf.z; af.w += vf.w;
        a2.x = fmaf(vp.x, c, a2.x); a2.y = fmaf(vp.y, c, a2.y);
        a2.z = fmaf(vp.z, c, a2.z); a2.w = fmaf(vp.w, c, a2.w);
    }
    // red[g*32 + seg] = partial for segment seg from row-group g
    const int base = g * 32 + k4 * 4;
    red0[base+0] = ap.x; red0[base+1] = ap.y; red0[base+2] = ap.z; red0[base+3] = ap.w;
    red1[base+0] = af.x; red1[base+1] = af.y; red1[base+2] = af.z; red1[base+3] = af.w;
    red2[base+0] = a2.x; red2[base+1] = a2.y; red2[base+2] = a2.z; red2[base+3] = a2.w;
    __syncthreads();

    if (t < KSEG) {
        float s0 = 0.f, s1 = 0.f, s2 = 0.f;
#pragma unroll
        for (int j = 0; j < 32; j++) {
            s0 += red0[j*32 + t];
            s1 += red1[j*32 + t];
            s2 += red2[j*32 + t];
        }
        // segpart[x][b][nc][k]
        ws[OFF_SEGP + ((0*BS + b)*16 + nc)*KSEG + t] = s0;
        ws[OFF_SEGP + ((1*BS + b)*16 + nc)*KSEG + t] = s1;
        ws[OFF_SEGP + ((2*BS + b)*16 + nc)*KSEG + t] = s2;
    }
}

// grid: BS*2 = 32 blocks; block handles 16 (b,k) cells, 16 threads per cell
// over D. Writes per-block partials; the LAST block (ticket) does the final
// reduction and writes the scalar — no separate final launch.
__global__ __launch_bounds__(256) void loss_kernel(
    const float* __restrict__ rf_tok, const float* __restrict__ rp_tok,
    float* __restrict__ ws, float* __restrict__ out)
{
    const int b  = blockIdx.x >> 1;
    const int kh = blockIdx.x & 1;
    const int t = threadIdx.x;
    const int cell = t >> 4;   // 0..15
    const int dg   = t & 15;
    const int k = kh * 16 + cell;

    // sum 16 per-nc partials (redundant across the 16 lanes of a cell:
    // same-address broadcast loads, L2-hot)
    float supp = 0.f, supf = 0.f;
#pragma unroll
    for (int nc = 0; nc < 16; nc++) {
        supp += ws[OFF_SEGP + ((0*BS + b)*16 + nc)*KSEG + k];
        supf += ws[OFF_SEGP + ((1*BS + b)*16 + nc)*KSEG + k];
    }
    const float spv = fmaxf(supp, 1.0f);
    const float sfv = fmaxf(supf, 1.0f);

    const float* rf = rf_tok + ((size_t)b * KSEG + k) * DDIM;
    const float* rp = rp_tok + ((size_t)b * KSEG + k) * DDIM;
    float acc = 0.f;
#pragma unroll
    for (int j = 0; j < 8; j++) {
        int d = dg + 16 * j;
        float v = rf[d] / sfv - rp[d] / spv;
        acc += v * v;
    }
#pragma unroll
    for (int off = 8; off; off >>= 1) acc += __shfl_xor(acc, off);

    __shared__ float lbuf[16], cbuf[16];
    __shared__ int isLast;
    if (dg == 0) {
        float s2d = 0.f;
#pragma unroll
        for (int nc = 0; nc < 16; nc++)
            s2d += ws[OFF_SEGP + ((2*BS + b)*16 + nc)*KSEG + k];
        bool valid = (supp >= 20.0f) && (supf >= 20.0f);
        float arg = s2d / spv / 0.05f;
        float rel = 1.0f / (1.0f + expf(-arg));
        float ld = acc - rel; ld = ld * ld;
        bool msk = valid && (ld <= 20.0f);
        lbuf[cell] = msk ? ld : 0.0f;
        cbuf[cell] = msk ? 1.0f : 0.0f;
    }
    __syncthreads();
    if (t == 0) {
        float st = 0.f, sc = 0.f;
#pragma unroll
        for (int i = 0; i < 16; i++) { st += lbuf[i]; sc += cbuf[i]; }
        ws[OFF_LOSSP + blockIdx.x]      = st;
        ws[OFF_LOSSP + 32 + blockIdx.x] = sc;
        __threadfence();
        unsigned int ticket =
            atomicAdd(&((unsigned int*)ws)[OFF_CNT], 1u);
        isLast = (ticket == 31u);
    }
    __syncthreads();
    if (isLast && t < 64) {
        // device-scope atomic reads: coherent across XCD L2s
        float v1 = (t < 32) ? atomicAdd(&ws[OFF_LOSSP + t],      0.0f) : 0.0f;
        float v2 = (t < 32) ? atomicAdd(&ws[OFF_LOSSP + 32 + t], 0.0f) : 0.0f;
#pragma unroll
        for (int off = 16; off; off >>= 1) {
            v1 += __shfl_xor(v1, off);
            v2 += __shfl_xor(v2, off);
        }
        if (t == 0) out[0] = v1 / (v2 + 1.0f) * 1.0f;  // WEIGHT = 1.0
    }
}

extern "C" void kernel_launch(void* const* d_in, const int* in_sizes, int n_in,
                              void* d_out, int out_size, void* d_ws, size_t ws_size,
                              hipStream_t stream) {
    const float* r_tokens_full    = (const float*)d_in[0];
    const float* r_tokens_partial = (const float*)d_in[1];
    const float* pc_seg_partial   = (const float*)d_in[2];
    const float* pc_seg_full      = (const float*)d_in[3];
    const float* pc_partial       = (const float*)d_in[4];
    const float* deformed         = (const float*)d_in[5];
    const float* p_rot            = (const float*)d_in[6];
    const float* p_t              = (const float*)d_in[7];
    const float* f_rot            = (const float*)d_in[8];
    const float* f_t              = (const float*)d_in[9];
    const float* tgt_rand_rot     = (const float*)d_in[10];
    const float* tgt_rand_t       = (const float*)d_in[11];
    const float* src_rand_rot     = (const float*)d_in[12];
    const float* src_rand_t       = (const float*)d_in[13];

    float* ws  = (float*)d_ws;
    float* out = (float*)d_out;

    cham_kernel<<<BS * 32, 256, 0, stream>>>(
        pc_partial, deformed, p_rot, p_t, f_rot, f_t,
        tgt_rand_rot, tgt_rand_t, src_rand_rot, src_rand_t,
        ws + OFF_XN, ws + OFF_PART);

    seg_kernel<<<BS * 16, 256, 0, stream>>>(
        pc_seg_partial, pc_seg_full, ws + OFF_XN, ws + OFF_PART, ws);

    loss_kernel<<<BS * 2, 256, 0, stream>>>(
        r_tokens_full, r_tokens_partial, ws, out);
}